// Round 19
// baseline (540.668 us; speedup 1.0000x reference)
//
#include <hip/hip_runtime.h>

#define AS1 __attribute__((address_space(1)))
#define AS3 __attribute__((address_space(3)))

typedef __attribute__((ext_vector_type(8))) short short8;
typedef __attribute__((ext_vector_type(4))) float f32x4;
typedef __attribute__((ext_vector_type(4))) int int4v;
typedef unsigned long long u64;

static __device__ __forceinline__ unsigned short f2bf(float f) {
    unsigned u = __builtin_bit_cast(unsigned, f);
    u += 0x7FFFu + ((u >> 16) & 1u);
    return (unsigned short)(u >> 16);
}

// ---------------- conversion kernels ----------------

__global__ void cvt_bf16_kernel(const float* __restrict__ in,
                                unsigned short* __restrict__ out, int n8) {
    int i = blockIdx.x * blockDim.x + threadIdx.x;
    int stride = gridDim.x * blockDim.x;
    for (; i < n8; i += stride) {
        const float4* p = (const float4*)in + 2 * (size_t)i;
        float4 a = p[0], b = p[1];
        short8 o;
        o[0] = f2bf(a.x); o[1] = f2bf(a.y); o[2] = f2bf(a.z); o[3] = f2bf(a.w);
        o[4] = f2bf(b.x); o[5] = f2bf(b.y); o[6] = f2bf(b.z); o[7] = f2bf(b.w);
        *(short8*)(out + 8 * (size_t)i) = o;
    }
}

// out[m,k] = bf16(wa[m,k] * wb[k]),  K = 512 fixed
__global__ void wab_kernel(const float* __restrict__ wa, const float* __restrict__ wb,
                           unsigned short* __restrict__ out, int n8) {
    int i = blockIdx.x * blockDim.x + threadIdx.x;
    int stride = gridDim.x * blockDim.x;
    for (; i < n8; i += stride) {
        int base = i * 8;
        int k = base & 511;
        const float4* pa = (const float4*)(wa + base);
        const float4* pb = (const float4*)(wb + k);
        float4 a0 = pa[0], a1 = pa[1], b0 = pb[0], b1 = pb[1];
        short8 o;
        o[0] = f2bf(a0.x * b0.x); o[1] = f2bf(a0.y * b0.y);
        o[2] = f2bf(a0.z * b0.z); o[3] = f2bf(a0.w * b0.w);
        o[4] = f2bf(a1.x * b1.x); o[5] = f2bf(a1.y * b1.y);
        o[6] = f2bf(a1.z * b1.z); o[7] = f2bf(a1.w * b1.w);
        *(short8*)(out + 8 * (size_t)i) = o;
    }
}

// wc[512][N] -> out[N][512] bf16, coalesced via 64x64 LDS tile (+1-pad: free 2-way)
__global__ __launch_bounds__(256) void wcT_kernel(const float* __restrict__ wc,
                                                  unsigned short* __restrict__ out, int N) {
    __shared__ float tile[64][65];
    const int tn = blockIdx.x * 64, tk = blockIdx.y * 64;
    const int c = threadIdx.x & 63, r0 = threadIdx.x >> 6;
#pragma unroll
    for (int r = r0; r < 64; r += 4)
        tile[r][c] = wc[(size_t)(tk + r) * N + tn + c];
    __syncthreads();
#pragma unroll
    for (int r = r0; r < 64; r += 4)
        out[(size_t)(tn + r) * 512 + tk + c] = f2bf(tile[c][r]);
}

__global__ void bih_kernel(const float* __restrict__ b1, const float* __restrict__ ib1,
                           float* __restrict__ out) {
    int i = blockIdx.x * blockDim.x + threadIdx.x;
    if (i < 1536) out[i] = (i < 1024) ? b1[i] : ib1[i - 1024];
}

__global__ void scan_init_kernel(unsigned short* __restrict__ hbf,
                                 unsigned* __restrict__ ctrl) {
    int i = blockIdx.x * blockDim.x + threadIdx.x;
    if (i < 65536) hbf[i] = 0;
    if (i < 2176) ctrl[i] = 0;
}

// ---------------- NT GEMM: C[M,N] = A[M,K](bf16) * B[N,K]^T(bf16) (+bias) ----------------
// 1D grid, XCD-aware bijective swizzle (requires gridDim.x % 8 == 0).

template <typename OutT, bool BIAS>
__global__ __launch_bounds__(256) void gemm_nt_kernel(
    const unsigned short* __restrict__ A, const unsigned short* __restrict__ B,
    OutT* __restrict__ C, const float* __restrict__ bias, int K, int ldC, int gn) {
    __shared__ __align__(16) unsigned short As[128 * 64];
    __shared__ __align__(16) unsigned short Bs[128 * 64];
    const int tid = threadIdx.x;
    const int wave = tid >> 6, lane = tid & 63;
    const int nblk = gridDim.x;
    const int bid = blockIdx.x;
    const int swz = (bid & 7) * (nblk >> 3) + (bid >> 3);   // bijective (nblk%8==0)
    const long bm = (long)(swz / gn) * 128, bn = (long)(swz % gn) * 128;
    const int wr = (wave >> 1) * 64, wc = (wave & 1) * 64;
    f32x4 acc[4][4] = {};

    const int srow = tid >> 3;
    const int scol = (tid & 7) * 8;
    const unsigned short* Ag = A + bm * K + scol;
    const unsigned short* Bg = B + bn * K + scol;

    for (int kt = 0; kt < K; kt += 64) {
        __syncthreads();
#pragma unroll
        for (int i = 0; i < 4; ++i) {
            __builtin_amdgcn_global_load_lds(
                (const AS1 void*)(Ag + (long)(i * 32 + srow) * K + kt),
                (AS3 void*)(As + i * 2048 + wave * 512), 16, 0, 0);
        }
#pragma unroll
        for (int i = 0; i < 4; ++i) {
            __builtin_amdgcn_global_load_lds(
                (const AS1 void*)(Bg + (long)(i * 32 + srow) * K + kt),
                (AS3 void*)(Bs + i * 2048 + wave * 512), 16, 0, 0);
        }
        __syncthreads();
#pragma unroll
        for (int kk = 0; kk < 2; ++kk) {
            const int ko = kk * 32 + (lane >> 4) * 8;
            short8 af[4], bfr[4];
#pragma unroll
            for (int mi = 0; mi < 4; ++mi)
                af[mi] = *(const short8*)(As + (wr + mi * 16 + (lane & 15)) * 64 + ko);
#pragma unroll
            for (int ni = 0; ni < 4; ++ni)
                bfr[ni] = *(const short8*)(Bs + (wc + ni * 16 + (lane & 15)) * 64 + ko);
#pragma unroll
            for (int mi = 0; mi < 4; ++mi)
#pragma unroll
                for (int ni = 0; ni < 4; ++ni)
                    acc[mi][ni] = __builtin_amdgcn_mfma_f32_16x16x32_bf16(
                        af[mi], bfr[ni], acc[mi][ni], 0, 0, 0);
        }
    }

    const int rbase = (lane >> 4) * 4;
    const int cbase = lane & 15;
#pragma unroll
    for (int mi = 0; mi < 4; ++mi) {
#pragma unroll
        for (int ni = 0; ni < 4; ++ni) {
            long gc = bn + wc + ni * 16 + cbase;
            float bv = BIAS ? bias[gc] : 0.f;
#pragma unroll
            for (int j = 0; j < 4; ++j) {
                long gr = bm + wr + mi * 16 + rbase + j;
                float v = acc[mi][ni][j] + bv;
                if constexpr (sizeof(OutT) == 2)
                    C[gr * ldC + gc] = (OutT)f2bf(v);
                else
                    C[gr * ldC + gc] = v;
            }
        }
    }
}

// ---------------- persistent GRU scan v19: v13 + end-of-step vmem pre-drain --------------
// v13 protocol (verified 314us) with ONE hang-proof addition: after issuing the
// deferred out stores + slab prefetch, each wave drains vmcnt(0) at the END of the
// step. For non-slowest team members this overlaps the poll wait (free); for the
// slowest it replaces the identical drain the next stage's vmcnt(0) would pay.
// Net: removes out-RFO/slab HBM residual latency from the inter-block critical path.

__global__ __launch_bounds__(256, 1) void gru_scan_kernel(
    unsigned short* __restrict__ hbuf,        // 2 x [128][512] bf16 ping-pong
    const unsigned short* __restrict__ whh,   // [1536][512] bf16
    const float* __restrict__ bhh,
    const float* __restrict__ gi, const float* __restrict__ gf,
    float* __restrict__ out, float* __restrict__ hT,
    unsigned* __restrict__ ctrl) {
    __shared__ __align__(16) unsigned short h_lds[16 * 512];   // 16KB, swizzled
    __shared__ __align__(16) float gis[48 * 68];               // [bbq*3+g][68]
    __shared__ __align__(16) float gfs[32 * 68];               // [bbq*2+g][68]
    __shared__ unsigned fast_sh;

    const int tid = threadIdx.x;
    const int lane = tid & 63;
    const int wv = tid >> 6;
    const int bid = blockIdx.x;
    const int team = bid & 7;                 // XCD-local under round-robin mapping
    const int member = bid >> 3;
    const int r0 = team * 16;
    const int cb = member * 64;
    const int c0 = cb + wv * 16;
    const int lrow = lane & 15;
    const int q = lane >> 4;

    unsigned* flags = ctrl;                   // flag of block b at ctrl[b*32] (128B/line)
    unsigned* xcds = ctrl + 2048;
    unsigned* probes = ctrl + 2112;

    // register-resident whh fragments: 3 gates x 16 K-frags, cols [c0,c0+16)
    short8 wf[3][16];
#pragma unroll
    for (int g = 0; g < 3; ++g)
#pragma unroll
        for (int kk = 0; kk < 16; ++kk)
            wf[g][kk] = *(const short8*)(whh + (size_t)(g * 512 + c0 + lrow) * 512 + kk * 32 + q * 8);

    // ---- startup: verify team is XCD-local (else fall back to sc1+fence path) ----
    unsigned my_xcc;
    asm volatile("s_getreg_b32 %0, hwreg(20, 0, 32)" : "=s"(my_xcc));
    if (tid == 0) {
        probes[bid] = 0x5A5A0000u + (unsigned)bid;              // plain store -> own L2
        asm volatile("s_waitcnt vmcnt(0)" ::: "memory");
        __hip_atomic_store(&xcds[bid], my_xcc + 1u,
                           __ATOMIC_RELAXED, __HIP_MEMORY_SCOPE_AGENT);
    }
    {
        unsigned ok = 1;
        if (tid < 8) {
            int tb = tid * 8 + team;
            unsigned xv;
            do {
                xv = __hip_atomic_load(&xcds[tb], __ATOMIC_RELAXED,
                                       __HIP_MEMORY_SCOPE_AGENT);
                if (xv == 0) __builtin_amdgcn_s_sleep(1);
            } while (xv == 0);
            unsigned pv = *(volatile const unsigned*)&probes[tb]; // hits local L2 iff same XCD
            ok = (xv == my_xcc + 1u) && (pv == 0x5A5A0000u + (unsigned)tb);
        }
        ok = __all((int)ok) ? 1u : 0u;
        if (tid == 0) fast_sh = ok;
        __syncthreads();
    }
    const bool fast = fast_sh != 0;

    const int hc = c0 + lrow;
    const float br = bhh[hc], bz = bhh[512 + hc], bn_ = bhh[1024 + hc];
    const int rb = r0 + q * 4;
    const int lc = wv * 16 + lrow;            // col within block's 64-col slab
    float hprev[4] = {0.f, 0.f, 0.f, 0.f};

    // slab prefetch: 5 x float4/thread; chunk = 256B of (row bbq, gate) slice
    const int chunk_sub = tid >> 4;           // 0..15
    const int u4 = (tid & 15) * 4;
    float4 sl[5];
    auto slab_load = [&](int t) {
#pragma unroll
        for (int k = 0; k < 5; ++k) {
            int chunk = k * 16 + chunk_sub;   // 0..79
            const float* p;
            if (chunk < 48) {
                int bbq = chunk / 3, g = chunk - bbq * 3;
                p = gi + ((size_t)(r0 + bbq) * 64 + t) * 1536 + g * 512 + cb + u4;
            } else {
                int c2 = chunk - 48, bbq = c2 >> 1, g2 = c2 & 1;
                p = gf + ((size_t)(r0 + bbq) * 64 + t) * 1024 + g2 * 512 + cb + u4;
            }
            sl[k] = *(const float4*)p;
        }
    };
    slab_load(0);

    const int srow = tid >> 4;                // staging row 0..15
    const int cpos = tid & 15;                // 16 threads per 1KB row
    const int sw = (srow & 7) << 4;
    // wave0 poll address: lane l watches teammate (l&7)'s flag line
    const unsigned* fpoll = &flags[(size_t)((lane & 7) * 8 + team) * 32];

    for (int t = 0; t < 64; ++t) {
        const unsigned short* hin = hbuf + (t & 1) * 65536;

        if (fast) {
            // ---- wave0-only poll (8 lanes per flag, distinct 128B lines) ----
            if (t > 0) {
                if (wv == 0) {
                    const unsigned need = (unsigned)t;
                    for (;;) {
                        unsigned v = *(volatile const unsigned*)fpoll;
                        if (__all((int)(v >= need))) break;
                        __builtin_amdgcn_s_sleep(1);
                    }
                }
                __builtin_amdgcn_s_barrier();      // release waves 1-3 into staging
                __builtin_amdgcn_sched_barrier(0);
            }
            // ---- stage h(t): 4 x 16B sc0 loads (local-L2 hits), one waitcnt ----
            {
                const char* src = (const char*)(hin + (size_t)(r0 + srow) * 512) + cpos * 16;
                int4v h0, h1, h2, h3;
                asm volatile(
                    "global_load_dwordx4 %0, %4, off sc0\n\t"
                    "global_load_dwordx4 %1, %4, off offset:256 sc0\n\t"
                    "global_load_dwordx4 %2, %4, off offset:512 sc0\n\t"
                    "global_load_dwordx4 %3, %4, off offset:768 sc0\n\t"
                    "s_waitcnt vmcnt(0)"
                    : "=&v"(h0), "=&v"(h1), "=&v"(h2), "=&v"(h3)
                    : "v"(src) : "memory");
                __builtin_amdgcn_sched_barrier(0);
                char* dst = (char*)h_lds + srow * 1024;
                *(int4v*)(dst + (((cpos + 0) * 16) ^ sw)) = h0;
                *(int4v*)(dst + (((cpos + 16) * 16) ^ sw)) = h1;
                *(int4v*)(dst + (((cpos + 32) * 16) ^ sw)) = h2;
                *(int4v*)(dst + (((cpos + 48) * 16) ^ sw)) = h3;
            }
        } else {
            // ---- v5-proven slow path: sc1 poll + acquire fence + sc1 loads ----
            if (t > 0 && tid < 64) {
                const unsigned tgt = (unsigned)t;
                for (;;) {
                    unsigned v = __hip_atomic_load(&flags[(size_t)((lane & 7) * 8 + team) * 32],
                                                   __ATOMIC_RELAXED, __HIP_MEMORY_SCOPE_AGENT);
                    if (__all((int)(v >= tgt))) break;
                    __builtin_amdgcn_s_sleep(1);
                }
                __builtin_amdgcn_fence(__ATOMIC_ACQUIRE, "agent");
            }
            __syncthreads();
            {
                const u64* hs = (const u64*)(hin + (size_t)(r0 + srow) * 512);
                u64 hq[8];
#pragma unroll
                for (int k = 0; k < 8; ++k)
                    hq[k] = __hip_atomic_load(hs + cpos + k * 16,
                                              __ATOMIC_RELAXED, __HIP_MEMORY_SCOPE_AGENT);
                char* dst = (char*)h_lds + srow * 1024;
#pragma unroll
                for (int k = 0; k < 8; ++k) {
                    int byte = (cpos + k * 16) * 8;
                    *(u64*)(dst + (byte ^ sw)) = hq[k];
                }
            }
        }

        // ---- redistribute slab(t) regs -> LDS ----
#pragma unroll
        for (int k = 0; k < 5; ++k) {
            int chunk = k * 16 + chunk_sub;
            float* d = (chunk < 48) ? &gis[chunk * 68] : &gfs[(chunk - 48) * 68];
            *(float4*)(d + u4) = sl[k];
        }
        __syncthreads();   // barrier A: h_lds + gis/gfs ready

        if (!fast && t < 63) slab_load(t + 1);   // slow path: original placement

        // ---- matvec: h(t) @ whh^T for 3 gates ----
        f32x4 acc0 = {}, acc1 = {}, acc2 = {};
        {
            const char* hl = (const char*)h_lds + lrow * 1024;
            const int sw2 = (lrow & 7) << 4;
#pragma unroll
            for (int kk = 0; kk < 16; ++kk) {
                short8 a = *(const short8*)(hl + ((kk * 64 + q * 16) ^ sw2));
                acc0 = __builtin_amdgcn_mfma_f32_16x16x32_bf16(a, wf[0][kk], acc0, 0, 0, 0);
                acc1 = __builtin_amdgcn_mfma_f32_16x16x32_bf16(a, wf[1][kk], acc1, 0, 0, 0);
                acc2 = __builtin_amdgcn_mfma_f32_16x16x32_bf16(a, wf[2][kk], acc2, 0, 0, 0);
            }
        }

        // ---- gates; fast path publishes ONLY h before the flag ----
        float hy4[4];
        unsigned short* hout = hbuf + ((t & 1) ^ 1) * 65536;
#pragma unroll
        for (int j = 0; j < 4; ++j) {
            const int bbq = q * 4 + j;
            float ir  = gis[(bbq * 3 + 0) * 68 + lc];
            float ii  = gis[(bbq * 3 + 1) * 68 + lc];
            float inn = gis[(bbq * 3 + 2) * 68 + lc];
            float fr  = gfs[(bbq * 2 + 0) * 68 + lc];
            float fi  = gfs[(bbq * 2 + 1) * 68 + lc];
            float r = 1.f / (1.f + __expf(-(ir + acc0[j] + br + fr)));
            float z = 1.f / (1.f + __expf(-(ii + acc1[j] + bz + fi)));
            float n = tanhf(inn + r * (acc2[j] + bn_));
            float hy = n + z * (hprev[j] - n);
            hprev[j] = hy;
            hy4[j] = hy;
            if (fast) {
                if (t < 63) hout[(size_t)(rb + j) * 512 + hc] = f2bf(hy);
            } else {
                if (t < 63)
                    __hip_atomic_store(hout + (size_t)(rb + j) * 512 + hc,
                                       (unsigned short)f2bf(hy),
                                       __ATOMIC_RELAXED, __HIP_MEMORY_SCOPE_AGENT);
                __builtin_nontemporal_store(hy, &out[((size_t)(rb + j) * 64 + t) * 512 + hc]);
                if (t == 63)
                    __builtin_nontemporal_store(hy, &hT[(size_t)(rb + j) * 512 + hc]);
            }
        }

        if (fast) {
            if (t < 63) {
                __syncthreads();   // barrier B: drains ONLY the h publish (local L2)
                if (tid == 0) *(volatile unsigned*)&flags[(size_t)bid * 32] = (unsigned)(t + 1);
                slab_load(t + 1);  // deferred; drained below, off the flag path
            }
            // deferred out/hT stores
#pragma unroll
            for (int j = 0; j < 4; ++j)
                out[((size_t)(rb + j) * 64 + t) * 512 + hc] = hy4[j];
            if (t == 63) {
#pragma unroll
                for (int j = 0; j < 4; ++j)
                    hT[(size_t)(rb + j) * 512 + hc] = hy4[j];
            }
            // NEW: pre-drain out-RFO + slab under the teammates' publish window,
            // so the next stage's vmcnt(0) sees only its own 4 sc0 reads.
            if (t < 63) {
                asm volatile("s_waitcnt vmcnt(0)" ::: "memory");
            }
        } else {
            if (t < 63) {
                __syncthreads();   // barrier B: all stores drained
                if (tid == 0) {
                    __builtin_amdgcn_fence(__ATOMIC_RELEASE, "agent");
                    __hip_atomic_store(&flags[(size_t)bid * 32], (unsigned)(t + 1),
                                       __ATOMIC_RELAXED, __HIP_MEMORY_SCOPE_AGENT);
                }
            }
        }
    }
}

// ---------------- host launcher ----------------

extern "C" void kernel_launch(void* const* d_in, const int* in_sizes, int n_in,
                              void* d_out, int out_size, void* d_ws, size_t ws_size,
                              hipStream_t stream) {
    (void)in_sizes; (void)n_in; (void)out_size; (void)ws_size;

    const float* x0  = (const float*)d_in[0];
    const float* x1  = (const float*)d_in[1];
    const float* wa0 = (const float*)d_in[2];
    const float* wb0 = (const float*)d_in[3];
    const float* wc0 = (const float*)d_in[4];
    const float* b0  = (const float*)d_in[5];
    const float* wa1 = (const float*)d_in[6];
    const float* wb1 = (const float*)d_in[7];
    const float* wc1 = (const float*)d_in[8];
    const float* b1  = (const float*)d_in[9];
    const float* iw1 = (const float*)d_in[10];
    const float* ib1 = (const float*)d_in[11];
    const float* whh = (const float*)d_in[12];
    const float* bhh = (const float*)d_in[13];

    float* out = (float*)d_out;                  // [128,64,512]
    float* hT  = out + (size_t)128 * 64 * 512;   // [128,512]

    char* w = (char*)d_ws;
    auto alloc = [&](size_t bytes) {
        char* p = w;
        w += (bytes + 255) & ~(size_t)255;
        return p;
    };
    unsigned short* x1bf = (unsigned short*)alloc((size_t)8192 * 2048 * 2);
    unsigned short* x0bf = (unsigned short*)alloc((size_t)8192 * 1536 * 2);
    unsigned short* wih  = (unsigned short*)alloc((size_t)1536 * 2048 * 2);
    unsigned short* wfh  = (unsigned short*)alloc((size_t)1024 * 1536 * 2);
    unsigned short* wab0 = (unsigned short*)alloc((size_t)1024 * 512 * 2);
    unsigned short* wab1 = (unsigned short*)alloc((size_t)1024 * 512 * 2);
    unsigned short* wc0T = (unsigned short*)alloc((size_t)1536 * 512 * 2);
    unsigned short* wc1T = (unsigned short*)alloc((size_t)2048 * 512 * 2);
    unsigned short* whhb = (unsigned short*)alloc((size_t)1536 * 512 * 2);
    float* bih = (float*)alloc(1536 * 4);
    unsigned short* hbf = (unsigned short*)alloc((size_t)2 * 65536 * 2);
    unsigned* ctrl = (unsigned*)alloc(2304 * 4);
    float* gi  = (float*)alloc((size_t)8192 * 1536 * 4);
    float* gf  = (float*)alloc((size_t)8192 * 1024 * 4);

    // conversions
    cvt_bf16_kernel<<<2048, 256, 0, stream>>>(x1, x1bf, (8192 * 2048) / 8);
    cvt_bf16_kernel<<<2048, 256, 0, stream>>>(x0, x0bf, (8192 * 1536) / 8);
    wab_kernel<<<256, 256, 0, stream>>>(wa0, wb0, wab0, (1024 * 512) / 8);
    wab_kernel<<<256, 256, 0, stream>>>(wa1, wb1, wab1, (1024 * 512) / 8);
    wcT_kernel<<<dim3(24, 8), 256, 0, stream>>>(wc0, wc0T, 1536);
    wcT_kernel<<<dim3(32, 8), 256, 0, stream>>>(wc1, wc1T, 2048);
    cvt_bf16_kernel<<<384, 256, 0, stream>>>(whh, whhb, (1536 * 512) / 8);
    cvt_bf16_kernel<<<512, 256, 0, stream>>>(iw1, wih + (size_t)1024 * 2048, (512 * 2048) / 8);
    bih_kernel<<<6, 256, 0, stream>>>(b1, ib1, bih);
    scan_init_kernel<<<256, 256, 0, stream>>>(hbf, ctrl);

    // weight GEMMs: w_fh[1024,1536] (96 blocks), w_ih[0:1024,2048] (128)
    gemm_nt_kernel<unsigned short, false><<<96, 256, 0, stream>>>(
        wab0, wc0T, wfh, nullptr, 512, 1536, 12);
    gemm_nt_kernel<unsigned short, false><<<128, 256, 0, stream>>>(
        wab1, wc1T, wih, nullptr, 512, 2048, 16);

    // big projections: gi[8192,1536] (768 blocks), gf[8192,1024] (512)
    gemm_nt_kernel<float, true><<<768, 256, 0, stream>>>(
        x1bf, wih, gi, bih, 2048, 1536, 12);
    gemm_nt_kernel<float, true><<<512, 256, 0, stream>>>(
        x0bf, wfh, gf, b0, 1536, 1024, 8);

    // persistent scan: 64 blocks (1 block/CU, all co-resident)
    gru_scan_kernel<<<64, 256, 0, stream>>>(hbf, whhb, bhh, gi, gf, out, hT, ctrl);
}

// Round 20
// 532.388 us; speedup vs baseline: 1.0156x; 1.0156x over previous
//
#include <hip/hip_runtime.h>

#define AS1 __attribute__((address_space(1)))
#define AS3 __attribute__((address_space(3)))

typedef __attribute__((ext_vector_type(8))) short short8;
typedef __attribute__((ext_vector_type(4))) float f32x4;
typedef __attribute__((ext_vector_type(4))) int int4v;
typedef unsigned long long u64;

static __device__ __forceinline__ unsigned short f2bf(float f) {
    unsigned u = __builtin_bit_cast(unsigned, f);
    u += 0x7FFFu + ((u >> 16) & 1u);
    return (unsigned short)(u >> 16);
}

// ---------------- conversion kernels ----------------

__global__ void cvt_bf16_kernel(const float* __restrict__ in,
                                unsigned short* __restrict__ out, int n8) {
    int i = blockIdx.x * blockDim.x + threadIdx.x;
    int stride = gridDim.x * blockDim.x;
    for (; i < n8; i += stride) {
        const float4* p = (const float4*)in + 2 * (size_t)i;
        float4 a = p[0], b = p[1];
        short8 o;
        o[0] = f2bf(a.x); o[1] = f2bf(a.y); o[2] = f2bf(a.z); o[3] = f2bf(a.w);
        o[4] = f2bf(b.x); o[5] = f2bf(b.y); o[6] = f2bf(b.z); o[7] = f2bf(b.w);
        *(short8*)(out + 8 * (size_t)i) = o;
    }
}

// out[m,k] = bf16(wa[m,k] * wb[k]),  K = 512 fixed
__global__ void wab_kernel(const float* __restrict__ wa, const float* __restrict__ wb,
                           unsigned short* __restrict__ out, int n8) {
    int i = blockIdx.x * blockDim.x + threadIdx.x;
    int stride = gridDim.x * blockDim.x;
    for (; i < n8; i += stride) {
        int base = i * 8;
        int k = base & 511;
        const float4* pa = (const float4*)(wa + base);
        const float4* pb = (const float4*)(wb + k);
        float4 a0 = pa[0], a1 = pa[1], b0 = pb[0], b1 = pb[1];
        short8 o;
        o[0] = f2bf(a0.x * b0.x); o[1] = f2bf(a0.y * b0.y);
        o[2] = f2bf(a0.z * b0.z); o[3] = f2bf(a0.w * b0.w);
        o[4] = f2bf(a1.x * b1.x); o[5] = f2bf(a1.y * b1.y);
        o[6] = f2bf(a1.z * b1.z); o[7] = f2bf(a1.w * b1.w);
        *(short8*)(out + 8 * (size_t)i) = o;
    }
}

// wc[512][N] -> out[N][512] bf16, coalesced via 64x64 LDS tile (+1-pad: free 2-way)
__global__ __launch_bounds__(256) void wcT_kernel(const float* __restrict__ wc,
                                                  unsigned short* __restrict__ out, int N) {
    __shared__ float tile[64][65];
    const int tn = blockIdx.x * 64, tk = blockIdx.y * 64;
    const int c = threadIdx.x & 63, r0 = threadIdx.x >> 6;
#pragma unroll
    for (int r = r0; r < 64; r += 4)
        tile[r][c] = wc[(size_t)(tk + r) * N + tn + c];
    __syncthreads();
#pragma unroll
    for (int r = r0; r < 64; r += 4)
        out[(size_t)(tn + r) * 512 + tk + c] = f2bf(tile[c][r]);
}

__global__ void bih_kernel(const float* __restrict__ b1, const float* __restrict__ ib1,
                           float* __restrict__ out) {
    int i = blockIdx.x * blockDim.x + threadIdx.x;
    if (i < 1536) out[i] = (i < 1024) ? b1[i] : ib1[i - 1024];
}

__global__ void scan_init_kernel(unsigned short* __restrict__ hbf,
                                 unsigned* __restrict__ ctrl) {
    int i = blockIdx.x * blockDim.x + threadIdx.x;
    if (i < 65536) hbf[i] = 0;
    if (i < 2176) ctrl[i] = 0;
}

// ---------------- NT GEMM: C[M,N] = A[M,K](bf16) * B[N,K]^T(bf16) (+bias) ----------------
// 1D grid, XCD-aware bijective swizzle (requires gridDim.x % 8 == 0).

template <typename OutT, bool BIAS>
__global__ __launch_bounds__(256) void gemm_nt_kernel(
    const unsigned short* __restrict__ A, const unsigned short* __restrict__ B,
    OutT* __restrict__ C, const float* __restrict__ bias, int K, int ldC, int gn) {
    __shared__ __align__(16) unsigned short As[128 * 64];
    __shared__ __align__(16) unsigned short Bs[128 * 64];
    const int tid = threadIdx.x;
    const int wave = tid >> 6, lane = tid & 63;
    const int nblk = gridDim.x;
    const int bid = blockIdx.x;
    const int swz = (bid & 7) * (nblk >> 3) + (bid >> 3);   // bijective (nblk%8==0)
    const long bm = (long)(swz / gn) * 128, bn = (long)(swz % gn) * 128;
    const int wr = (wave >> 1) * 64, wc = (wave & 1) * 64;
    f32x4 acc[4][4] = {};

    const int srow = tid >> 3;
    const int scol = (tid & 7) * 8;
    const unsigned short* Ag = A + bm * K + scol;
    const unsigned short* Bg = B + bn * K + scol;

    for (int kt = 0; kt < K; kt += 64) {
        __syncthreads();
#pragma unroll
        for (int i = 0; i < 4; ++i) {
            __builtin_amdgcn_global_load_lds(
                (const AS1 void*)(Ag + (long)(i * 32 + srow) * K + kt),
                (AS3 void*)(As + i * 2048 + wave * 512), 16, 0, 0);
        }
#pragma unroll
        for (int i = 0; i < 4; ++i) {
            __builtin_amdgcn_global_load_lds(
                (const AS1 void*)(Bg + (long)(i * 32 + srow) * K + kt),
                (AS3 void*)(Bs + i * 2048 + wave * 512), 16, 0, 0);
        }
        __syncthreads();
#pragma unroll
        for (int kk = 0; kk < 2; ++kk) {
            const int ko = kk * 32 + (lane >> 4) * 8;
            short8 af[4], bfr[4];
#pragma unroll
            for (int mi = 0; mi < 4; ++mi)
                af[mi] = *(const short8*)(As + (wr + mi * 16 + (lane & 15)) * 64 + ko);
#pragma unroll
            for (int ni = 0; ni < 4; ++ni)
                bfr[ni] = *(const short8*)(Bs + (wc + ni * 16 + (lane & 15)) * 64 + ko);
#pragma unroll
            for (int mi = 0; mi < 4; ++mi)
#pragma unroll
                for (int ni = 0; ni < 4; ++ni)
                    acc[mi][ni] = __builtin_amdgcn_mfma_f32_16x16x32_bf16(
                        af[mi], bfr[ni], acc[mi][ni], 0, 0, 0);
        }
    }

    const int rbase = (lane >> 4) * 4;
    const int cbase = lane & 15;
#pragma unroll
    for (int mi = 0; mi < 4; ++mi) {
#pragma unroll
        for (int ni = 0; ni < 4; ++ni) {
            long gc = bn + wc + ni * 16 + cbase;
            float bv = BIAS ? bias[gc] : 0.f;
#pragma unroll
            for (int j = 0; j < 4; ++j) {
                long gr = bm + wr + mi * 16 + rbase + j;
                float v = acc[mi][ni][j] + bv;
                if constexpr (sizeof(OutT) == 2)
                    C[gr * ldC + gc] = (OutT)f2bf(v);
                else
                    C[gr * ldC + gc] = v;
            }
        }
    }
}

// ---------------- persistent GRU scan v20: v18 + agent-atomic fast poll ----------------
// Identical to the verified r18 kernel (532.5us total / 314us scan) except the
// fast-path wave0 poll reads flags via __hip_atomic_load(RELAXED, AGENT) -- the
// compiler-generated L1-bypassing load (the v3/v5 slow paths used exactly this
// mechanism at 64-block scale, never hung). Tests the stale-L1 detection theory
// with zero deadlock risk: monotone flag, staleness only ever delays detection.

__global__ __launch_bounds__(256, 1) void gru_scan_kernel(
    unsigned short* __restrict__ hbuf,        // 2 x [128][512] bf16 ping-pong
    const unsigned short* __restrict__ whh,   // [1536][512] bf16
    const float* __restrict__ bhh,
    const float* __restrict__ gi, const float* __restrict__ gf,
    float* __restrict__ out, float* __restrict__ hT,
    unsigned* __restrict__ ctrl) {
    __shared__ __align__(16) unsigned short h_lds[16 * 512];   // 16KB, swizzled
    __shared__ __align__(16) float gis[48 * 68];               // [bbq*3+g][68]
    __shared__ __align__(16) float gfs[32 * 68];               // [bbq*2+g][68]
    __shared__ unsigned fast_sh;

    const int tid = threadIdx.x;
    const int lane = tid & 63;
    const int wv = tid >> 6;
    const int bid = blockIdx.x;
    const int team = bid & 7;                 // XCD-local under round-robin mapping
    const int member = bid >> 3;
    const int r0 = team * 16;
    const int cb = member * 64;
    const int c0 = cb + wv * 16;
    const int lrow = lane & 15;
    const int q = lane >> 4;

    unsigned* flags = ctrl;                   // flag of block b at ctrl[b*32] (128B/line)
    unsigned* xcds = ctrl + 2048;
    unsigned* probes = ctrl + 2112;

    // register-resident whh fragments: 3 gates x 16 K-frags, cols [c0,c0+16)
    short8 wf[3][16];
#pragma unroll
    for (int g = 0; g < 3; ++g)
#pragma unroll
        for (int kk = 0; kk < 16; ++kk)
            wf[g][kk] = *(const short8*)(whh + (size_t)(g * 512 + c0 + lrow) * 512 + kk * 32 + q * 8);

    // ---- startup: verify team is XCD-local (else fall back to sc1+fence path) ----
    unsigned my_xcc;
    asm volatile("s_getreg_b32 %0, hwreg(20, 0, 32)" : "=s"(my_xcc));
    if (tid == 0) {
        probes[bid] = 0x5A5A0000u + (unsigned)bid;              // plain store -> own L2
        asm volatile("s_waitcnt vmcnt(0)" ::: "memory");
        __hip_atomic_store(&xcds[bid], my_xcc + 1u,
                           __ATOMIC_RELAXED, __HIP_MEMORY_SCOPE_AGENT);
    }
    {
        unsigned ok = 1;
        if (tid < 8) {
            int tb = tid * 8 + team;
            unsigned xv;
            do {
                xv = __hip_atomic_load(&xcds[tb], __ATOMIC_RELAXED,
                                       __HIP_MEMORY_SCOPE_AGENT);
                if (xv == 0) __builtin_amdgcn_s_sleep(1);
            } while (xv == 0);
            unsigned pv = *(volatile const unsigned*)&probes[tb]; // hits local L2 iff same XCD
            ok = (xv == my_xcc + 1u) && (pv == 0x5A5A0000u + (unsigned)tb);
        }
        ok = __all((int)ok) ? 1u : 0u;
        if (tid == 0) fast_sh = ok;
        __syncthreads();
    }
    const bool fast = fast_sh != 0;

    const int hc = c0 + lrow;
    const float br = bhh[hc], bz = bhh[512 + hc], bn_ = bhh[1024 + hc];
    const int rb = r0 + q * 4;
    const int lc = wv * 16 + lrow;            // col within block's 64-col slab
    float hprev[4] = {0.f, 0.f, 0.f, 0.f};

    // slab prefetch: 5 x float4/thread; chunk = 256B of (row bbq, gate) slice
    const int chunk_sub = tid >> 4;           // 0..15
    const int u4 = (tid & 15) * 4;
    float4 sl[5];
    auto slab_load = [&](int t) {
#pragma unroll
        for (int k = 0; k < 5; ++k) {
            int chunk = k * 16 + chunk_sub;   // 0..79
            const float* p;
            if (chunk < 48) {
                int bbq = chunk / 3, g = chunk - bbq * 3;
                p = gi + ((size_t)(r0 + bbq) * 64 + t) * 1536 + g * 512 + cb + u4;
            } else {
                int c2 = chunk - 48, bbq = c2 >> 1, g2 = c2 & 1;
                p = gf + ((size_t)(r0 + bbq) * 64 + t) * 1024 + g2 * 512 + cb + u4;
            }
            sl[k] = *(const float4*)p;
        }
    };
    slab_load(0);

    const int srow = tid >> 4;                // staging row 0..15
    const int cpos = tid & 15;                // 16 threads per 1KB row
    const int sw = (srow & 7) << 4;
    // wave0 poll address: lane l watches teammate (l&7)'s flag line
    const unsigned* fpoll = &flags[(size_t)((lane & 7) * 8 + team) * 32];

    for (int t = 0; t < 64; ++t) {
        const unsigned short* hin = hbuf + (t & 1) * 65536;

        if (fast) {
            // ---- wave0-only poll via agent-scope atomic loads (L1-bypass) ----
            if (t > 0) {
                if (wv == 0) {
                    const unsigned need = (unsigned)t;
                    for (;;) {
                        unsigned v = __hip_atomic_load(fpoll, __ATOMIC_RELAXED,
                                                       __HIP_MEMORY_SCOPE_AGENT);
                        if (__all((int)(v >= need))) break;
                        __builtin_amdgcn_s_sleep(1);
                    }
                }
                __builtin_amdgcn_s_barrier();      // release waves 1-3 into staging
                __builtin_amdgcn_sched_barrier(0);
            }
            // ---- stage h(t): 4 x 16B sc0 loads (local-L2 hits), one waitcnt ----
            {
                const char* src = (const char*)(hin + (size_t)(r0 + srow) * 512) + cpos * 16;
                int4v h0, h1, h2, h3;
                asm volatile(
                    "global_load_dwordx4 %0, %4, off sc0\n\t"
                    "global_load_dwordx4 %1, %4, off offset:256 sc0\n\t"
                    "global_load_dwordx4 %2, %4, off offset:512 sc0\n\t"
                    "global_load_dwordx4 %3, %4, off offset:768 sc0\n\t"
                    "s_waitcnt vmcnt(0)"
                    : "=&v"(h0), "=&v"(h1), "=&v"(h2), "=&v"(h3)
                    : "v"(src) : "memory");
                __builtin_amdgcn_sched_barrier(0);
                char* dst = (char*)h_lds + srow * 1024;
                *(int4v*)(dst + (((cpos + 0) * 16) ^ sw)) = h0;
                *(int4v*)(dst + (((cpos + 16) * 16) ^ sw)) = h1;
                *(int4v*)(dst + (((cpos + 32) * 16) ^ sw)) = h2;
                *(int4v*)(dst + (((cpos + 48) * 16) ^ sw)) = h3;
            }
        } else {
            // ---- v5-proven slow path: sc1 poll + acquire fence + sc1 loads ----
            if (t > 0 && tid < 64) {
                const unsigned tgt = (unsigned)t;
                for (;;) {
                    unsigned v = __hip_atomic_load(&flags[(size_t)((lane & 7) * 8 + team) * 32],
                                                   __ATOMIC_RELAXED, __HIP_MEMORY_SCOPE_AGENT);
                    if (__all((int)(v >= tgt))) break;
                    __builtin_amdgcn_s_sleep(1);
                }
                __builtin_amdgcn_fence(__ATOMIC_ACQUIRE, "agent");
            }
            __syncthreads();
            {
                const u64* hs = (const u64*)(hin + (size_t)(r0 + srow) * 512);
                u64 hq[8];
#pragma unroll
                for (int k = 0; k < 8; ++k)
                    hq[k] = __hip_atomic_load(hs + cpos + k * 16,
                                              __ATOMIC_RELAXED, __HIP_MEMORY_SCOPE_AGENT);
                char* dst = (char*)h_lds + srow * 1024;
#pragma unroll
                for (int k = 0; k < 8; ++k) {
                    int byte = (cpos + k * 16) * 8;
                    *(u64*)(dst + (byte ^ sw)) = hq[k];
                }
            }
        }

        // ---- redistribute slab(t) regs -> LDS ----
#pragma unroll
        for (int k = 0; k < 5; ++k) {
            int chunk = k * 16 + chunk_sub;
            float* d = (chunk < 48) ? &gis[chunk * 68] : &gfs[(chunk - 48) * 68];
            *(float4*)(d + u4) = sl[k];
        }
        __syncthreads();   // barrier A: h_lds + gis/gfs ready

        if (!fast && t < 63) slab_load(t + 1);   // slow path: original placement

        // ---- matvec: h(t) @ whh^T for 3 gates ----
        f32x4 acc0 = {}, acc1 = {}, acc2 = {};
        {
            const char* hl = (const char*)h_lds + lrow * 1024;
            const int sw2 = (lrow & 7) << 4;
#pragma unroll
            for (int kk = 0; kk < 16; ++kk) {
                short8 a = *(const short8*)(hl + ((kk * 64 + q * 16) ^ sw2));
                acc0 = __builtin_amdgcn_mfma_f32_16x16x32_bf16(a, wf[0][kk], acc0, 0, 0, 0);
                acc1 = __builtin_amdgcn_mfma_f32_16x16x32_bf16(a, wf[1][kk], acc1, 0, 0, 0);
                acc2 = __builtin_amdgcn_mfma_f32_16x16x32_bf16(a, wf[2][kk], acc2, 0, 0, 0);
            }
        }

        // ---- gates; fast path publishes ONLY h before the flag ----
        float hy4[4];
        unsigned short* hout = hbuf + ((t & 1) ^ 1) * 65536;
#pragma unroll
        for (int j = 0; j < 4; ++j) {
            const int bbq = q * 4 + j;
            float ir  = gis[(bbq * 3 + 0) * 68 + lc];
            float ii  = gis[(bbq * 3 + 1) * 68 + lc];
            float inn = gis[(bbq * 3 + 2) * 68 + lc];
            float fr  = gfs[(bbq * 2 + 0) * 68 + lc];
            float fi  = gfs[(bbq * 2 + 1) * 68 + lc];
            float r = 1.f / (1.f + __expf(-(ir + acc0[j] + br + fr)));
            float z = 1.f / (1.f + __expf(-(ii + acc1[j] + bz + fi)));
            float n = tanhf(inn + r * (acc2[j] + bn_));
            float hy = n + z * (hprev[j] - n);
            hprev[j] = hy;
            hy4[j] = hy;
            if (fast) {
                if (t < 63) hout[(size_t)(rb + j) * 512 + hc] = f2bf(hy);
            } else {
                if (t < 63)
                    __hip_atomic_store(hout + (size_t)(rb + j) * 512 + hc,
                                       (unsigned short)f2bf(hy),
                                       __ATOMIC_RELAXED, __HIP_MEMORY_SCOPE_AGENT);
                __builtin_nontemporal_store(hy, &out[((size_t)(rb + j) * 64 + t) * 512 + hc]);
                if (t == 63)
                    __builtin_nontemporal_store(hy, &hT[(size_t)(rb + j) * 512 + hc]);
            }
        }

        if (fast) {
            if (t < 63) {
                __syncthreads();   // barrier B: drains ONLY the h publish (local L2)
                if (tid == 0) *(volatile unsigned*)&flags[(size_t)bid * 32] = (unsigned)(t + 1);
                slab_load(t + 1);  // deferred: drains at next poll, off critical path
            }
            // deferred out/hT stores (drain at next poll / kernel end)
#pragma unroll
            for (int j = 0; j < 4; ++j)
                out[((size_t)(rb + j) * 64 + t) * 512 + hc] = hy4[j];
            if (t == 63) {
#pragma unroll
                for (int j = 0; j < 4; ++j)
                    hT[(size_t)(rb + j) * 512 + hc] = hy4[j];
            }
        } else {
            if (t < 63) {
                __syncthreads();   // barrier B: all stores drained
                if (tid == 0) {
                    __builtin_amdgcn_fence(__ATOMIC_RELEASE, "agent");
                    __hip_atomic_store(&flags[(size_t)bid * 32], (unsigned)(t + 1),
                                       __ATOMIC_RELAXED, __HIP_MEMORY_SCOPE_AGENT);
                }
            }
        }
    }
}

// ---------------- host launcher ----------------

extern "C" void kernel_launch(void* const* d_in, const int* in_sizes, int n_in,
                              void* d_out, int out_size, void* d_ws, size_t ws_size,
                              hipStream_t stream) {
    (void)in_sizes; (void)n_in; (void)out_size; (void)ws_size;

    const float* x0  = (const float*)d_in[0];
    const float* x1  = (const float*)d_in[1];
    const float* wa0 = (const float*)d_in[2];
    const float* wb0 = (const float*)d_in[3];
    const float* wc0 = (const float*)d_in[4];
    const float* b0  = (const float*)d_in[5];
    const float* wa1 = (const float*)d_in[6];
    const float* wb1 = (const float*)d_in[7];
    const float* wc1 = (const float*)d_in[8];
    const float* b1  = (const float*)d_in[9];
    const float* iw1 = (const float*)d_in[10];
    const float* ib1 = (const float*)d_in[11];
    const float* whh = (const float*)d_in[12];
    const float* bhh = (const float*)d_in[13];

    float* out = (float*)d_out;                  // [128,64,512]
    float* hT  = out + (size_t)128 * 64 * 512;   // [128,512]

    char* w = (char*)d_ws;
    auto alloc = [&](size_t bytes) {
        char* p = w;
        w += (bytes + 255) & ~(size_t)255;
        return p;
    };
    unsigned short* x1bf = (unsigned short*)alloc((size_t)8192 * 2048 * 2);
    unsigned short* x0bf = (unsigned short*)alloc((size_t)8192 * 1536 * 2);
    unsigned short* wih  = (unsigned short*)alloc((size_t)1536 * 2048 * 2);
    unsigned short* wfh  = (unsigned short*)alloc((size_t)1024 * 1536 * 2);
    unsigned short* wab0 = (unsigned short*)alloc((size_t)1024 * 512 * 2);
    unsigned short* wab1 = (unsigned short*)alloc((size_t)1024 * 512 * 2);
    unsigned short* wc0T = (unsigned short*)alloc((size_t)1536 * 512 * 2);
    unsigned short* wc1T = (unsigned short*)alloc((size_t)2048 * 512 * 2);
    unsigned short* whhb = (unsigned short*)alloc((size_t)1536 * 512 * 2);
    float* bih = (float*)alloc(1536 * 4);
    unsigned short* hbf = (unsigned short*)alloc((size_t)2 * 65536 * 2);
    unsigned* ctrl = (unsigned*)alloc(2304 * 4);
    float* gi  = (float*)alloc((size_t)8192 * 1536 * 4);
    float* gf  = (float*)alloc((size_t)8192 * 1024 * 4);

    // conversions
    cvt_bf16_kernel<<<2048, 256, 0, stream>>>(x1, x1bf, (8192 * 2048) / 8);
    cvt_bf16_kernel<<<2048, 256, 0, stream>>>(x0, x0bf, (8192 * 1536) / 8);
    wab_kernel<<<256, 256, 0, stream>>>(wa0, wb0, wab0, (1024 * 512) / 8);
    wab_kernel<<<256, 256, 0, stream>>>(wa1, wb1, wab1, (1024 * 512) / 8);
    wcT_kernel<<<dim3(24, 8), 256, 0, stream>>>(wc0, wc0T, 1536);
    wcT_kernel<<<dim3(32, 8), 256, 0, stream>>>(wc1, wc1T, 2048);
    cvt_bf16_kernel<<<384, 256, 0, stream>>>(whh, whhb, (1536 * 512) / 8);
    cvt_bf16_kernel<<<512, 256, 0, stream>>>(iw1, wih + (size_t)1024 * 2048, (512 * 2048) / 8);
    bih_kernel<<<6, 256, 0, stream>>>(b1, ib1, bih);
    scan_init_kernel<<<256, 256, 0, stream>>>(hbf, ctrl);

    // weight GEMMs: w_fh[1024,1536] (96 blocks), w_ih[0:1024,2048] (128)
    gemm_nt_kernel<unsigned short, false><<<96, 256, 0, stream>>>(
        wab0, wc0T, wfh, nullptr, 512, 1536, 12);
    gemm_nt_kernel<unsigned short, false><<<128, 256, 0, stream>>>(
        wab1, wc1T, wih, nullptr, 512, 2048, 16);

    // big projections: gi[8192,1536] (768 blocks), gf[8192,1024] (512)
    gemm_nt_kernel<float, true><<<768, 256, 0, stream>>>(
        x1bf, wih, gi, bih, 2048, 1536, 12);
    gemm_nt_kernel<float, true><<<512, 256, 0, stream>>>(
        x0bf, wfh, gf, b0, 1536, 1024, 8);

    // persistent scan: 64 blocks (1 block/CU, all co-resident)
    gru_scan_kernel<<<64, 256, 0, stream>>>(hbf, whhb, bhh, gi, gf, out, hT, ctrl);
}